// Round 1
// baseline (105.850 us; speedup 1.0000x reference)
//
#include <hip/hip_runtime.h>

// HTMM: B_TREES=8, ARITY=4, DEPTH=8, C=8, M=100, NGEN=4
constexpr int OFFS1 = 8, OFFS2 = 40, OFFS3 = 168, OFFS4 = 680;
constexpr int OFFS5 = 2728, OFFS6 = 10920, OFFS7 = 43688, OFFS8 = 174760;

// lane mapping within a 32-lane group: r = g*8+s (g = gen, s = state), h = s>>2
// wtd_l[(j*8+d)*32 + g*8+s] = P(child=s | parent=d, pos j, gen g)
// emt_l[m*32 + g*8+c] = P(obs m | state c, gen g);  pit_l[g*8+c] = root prior
// etab_l[(m*4+j)*32 + g*8+d] = sum_c P(c|d,j,g)*em(m|c,g)  (leaf upward operator)
//
// All octet (8-lane) exchanges are done with DPP (quad_perm + row_half_mirror),
// never LDS: oct8() yields the octet's 8 values in a PERMUTED order
// (own quad k=0..3 first, other quad reversed); all weight registers are
// pre-permuted to match, and dot8p() reads natural-order LDS rows permuted.

#define AG_ST(p, v) __hip_atomic_store((p), (v), __ATOMIC_RELAXED, __HIP_MEMORY_SCOPE_AGENT)
#define AG_LD(p) __hip_atomic_load((p), __ATOMIC_RELAXED, __HIP_MEMORY_SCOPE_AGENT)

template <int CTRL>
static __device__ __forceinline__ float dppmov(float v) {
  return __int_as_float(__builtin_amdgcn_update_dpp(0, __float_as_int(v), CTRL, 0xF, 0xF, true));
}

// octet all-reduce sum, result broadcast to all 8 lanes. Pure DPP (no LDS).
// After xor1+xor2 each quad lane holds the quad sum, so the half-mirror
// partner (other quad) carries the same value as the xor4 partner: bit-exact.
static __device__ __forceinline__ float bfly8(float v) {
  v += dppmov<0xB1>(v);   // quad_perm [1,0,3,2]  (xor 1)
  v += dppmov<0x4E>(v);   // quad_perm [2,3,0,1]  (xor 2)
  v += dppmov<0x141>(v);  // row_half_mirror      (cross-quad within octet)
  return v;
}

// gather own-octet values: pv[k] = v[oct | 4h+k], pv[4+k] = v[oct | 7-4h-k]
static __device__ __forceinline__ void oct8(float v, float pv[8]) {
  float m = dppmov<0x141>(v);  // half-mirror: m[l] = v[oct | 7-(l&7)]
  pv[0] = dppmov<0x00>(v); pv[1] = dppmov<0x55>(v);
  pv[2] = dppmov<0xAA>(v); pv[3] = dppmov<0xFF>(v);
  pv[4] = dppmov<0x00>(m); pv[5] = dppmov<0x55>(m);
  pv[6] = dppmov<0xAA>(m); pv[7] = dppmov<0xFF>(m);
}

static __device__ __forceinline__ float dot8(const float w[8], const float v[8]) {
  return w[0]*v[0] + w[1]*v[1] + w[2]*v[2] + w[3]*v[3] +
         w[4]*v[4] + w[5]*v[5] + w[6]*v[6] + w[7]*v[7];
}

static __device__ __forceinline__ void ld8(const float* p, float pv[8]) {
  const float4* q = (const float4*)p;
  float4 a = q[0], b = q[1];
  pv[0] = a.x; pv[1] = a.y; pv[2] = a.z; pv[3] = a.w;
  pv[4] = b.x; pv[5] = b.y; pv[6] = b.z; pv[7] = b.w;
}

// load 8 consecutive floats permuted to the oct8 register order
static __device__ __forceinline__ void ld8p(const float* p, float wp[8], int h) {
  const float4* q = (const float4*)p;
  float4 a = q[h], b = q[1 - h];
  wp[0] = a.x; wp[1] = a.y; wp[2] = a.z; wp[3] = a.w;
  wp[4] = b.w; wp[5] = b.z; wp[6] = b.y; wp[7] = b.x;
}

// dot of permuted weights with a natural-order 8-vector in LDS
static __device__ __forceinline__ float dot8p(const float wp[8], const float* p, int h) {
  const float4* q = (const float4*)p;
  float4 a = q[h], b = q[1 - h];
  return wp[0]*a.x + wp[1]*a.y + wp[2]*a.z + wp[3]*a.w +
         wp[4]*b.w + wp[5]*b.z + wp[6]*b.y + wp[7]*b.x;
}

static __device__ __forceinline__ float dot8r(const float w[8], const float* p) {
  const float4* q = (const float4*)p;
  float4 a = q[0], b = q[1];
  return w[0]*a.x + w[1]*a.y + w[2]*a.z + w[3]*a.w +
         w[4]*b.x + w[5]*b.y + w[6]*b.z + w[7]*b.w;
}

static __device__ __forceinline__ float rcpf(float x) { return __builtin_amdgcn_rcpf(x); }

// one top-down prior step with runtime child-position j (weights read permuted)
static __device__ __forceinline__ float step_down(const float* wtd_l, float v, int j,
                                                  int r, int h) {
  const float* wb = &wtd_l[j * 256 + r];
  float w[8];
#pragma unroll
  for (int k = 0; k < 4; k++) {
    w[k]     = wb[(4 * h + k) * 32];
    w[4 + k] = wb[(7 - 4 * h - k) * 32];
  }
  float pv[8];
  oct8(v, pv);
  return dot8(w, pv);
}

// Single fused kernel: 512 blocks x 256. Each 32-lane group does 2 level-5
// subtrees; block covers 16 L5 nodes = 4 L4 nodes (done in-block). Last block
// per tree (device atomic, poison-robust) finishes levels 3..0.
__global__ __launch_bounds__(256) void k_all(const int* __restrict__ x,
                                             const float* __restrict__ A,
                                             const float* __restrict__ Bm,
                                             const float* __restrict__ Pi,
                                             float* __restrict__ RAT4,
                                             float* __restrict__ blocksum,
                                             unsigned* __restrict__ ctr,
                                             float* __restrict__ out) {
  __shared__ __align__(16) float wtd_l[1024];
  __shared__ __align__(16) float emt_l[3200];
  __shared__ __align__(16) float pit_l[32];
  __shared__ __align__(16) float etab_l[12800];  // phase 2 reuses as RAT4 stage
  __shared__ __align__(16) float shbuf[2304];    // phase-2 stash + final reduce
  __shared__ __align__(16) float rat5buf[16][32];
  __shared__ __align__(16) float pri4buf[4][32];
  __shared__ float llb[4];
  __shared__ int lastf;

  int t = threadIdx.x;
  int r = t & 31, g = r >> 3, s = r & 7, grp = t >> 5;
  int h = s >> 2;                       // quad parity within octet
  int b = blockIdx.x, tree = b >> 6;    // 64 blocks per tree

  // ---------------- phase 0: build all tables in LDS (per block) ----------------
  if (t < 128) {  // A softmax over child state; thread owns column (d,j,gg)
    int d = t >> 4, j = (t >> 2) & 3, gg = t & 3;
    float v[8], sum = 0.f;
#pragma unroll
    for (int ss = 0; ss < 8; ss++) { v[ss] = __expf(A[((ss * 8 + d) * 4 + j) * 4 + gg]); sum += v[ss]; }
    float inv = rcpf(sum);
#pragma unroll
    for (int ss = 0; ss < 8; ss++) wtd_l[(j * 8 + d) * 32 + gg * 8 + ss] = v[ss] * inv;
  }
  if (t < 4) {  // Pi softmax
    float v[8], sum = 0.f;
#pragma unroll
    for (int c = 0; c < 8; c++) { v[c] = __expf(Pi[c * 4 + t]); sum += v[c]; }
    float inv = rcpf(sum);
#pragma unroll
    for (int c = 0; c < 8; c++) pit_l[t * 8 + c] = v[c] * inv;
    llb[t] = 0.f;
  }
  {  // emission softmax over m: 32 rows x 8 octet-partitions
    int row = t >> 3, part = t & 7, c = row >> 2, gg = row & 3;
    int m0 = part < 4 ? part * 13 : 52 + (part - 4) * 12;
    int mn = part < 4 ? 13 : 12;
    float sum = 0.f;
    for (int m = m0; m < m0 + mn; m++) sum += __expf(Bm[(c * 100 + m) * 4 + gg]);
    sum = bfly8(sum);
    float inv = rcpf(sum);
    for (int m = m0; m < m0 + mn; m++)
      emt_l[m * 32 + gg * 8 + c] = __expf(Bm[(c * 100 + m) * 4 + gg]) * inv;
  }
  __syncthreads();
  {  // Etab: 12800 entries; combo (j,d,gg) = t&127, m-half = t>>7
    int c7 = t & 127, half = t >> 7;
    int j = c7 >> 5, d = (c7 >> 2) & 7, gg = c7 & 3;
    float w[8];
    ld8(&wtd_l[(j * 8 + d) * 32 + gg * 8], w);
    for (int m = half * 50; m < half * 50 + 50; m++)
      etab_l[(m * 4 + j) * 32 + gg * 8 + d] = dot8r(w, &emt_l[m * 32 + gg * 8]);
  }
  // permuted-order transition registers (wtd_l is stable from here on):
  //  wtd_p[j][i] = P(child=s | parent=perm(i), j, g)  (for parent-sum dots)
  //  wup_p[j][i] = P(child=perm(i) | parent=s, j, g)  (for child-sum dots)
  float wtd_p[4][8], wup_p[4][8];
#pragma unroll
  for (int j = 0; j < 4; j++) {
    const float* wb = &wtd_l[j * 256 + r];
#pragma unroll
    for (int k = 0; k < 4; k++) {
      wtd_p[j][k]     = wb[(4 * h + k) * 32];
      wtd_p[j][4 + k] = wb[(7 - 4 * h - k) * 32];
    }
    ld8p(&wtd_l[(j * 8 + s) * 32 + g * 8], wup_p[j], h);
  }
  __syncthreads();  // etab_l ready

  // ---------------- phase 1: two level-5 subtrees per group ----------------
  float acc = 0.f;
#pragma unroll 1
  for (int round = 0; round < 2; round++) {
    int n5 = b * 16 + round * 8 + grp;

    // prefetch this subtree's observation indices (no barriers below, so the
    // scheduler can sink uses freely; xls is software-pipelined one q6 ahead)
    const int4* x8v = (const int4*)(x + OFFS8 + n5 * 64);
    const int4* x7p = (const int4*)(x + OFFS7 + n5 * 16);
    int4 x6v = *(const int4*)(x + OFFS6 + n5 * 4);
    int x5s = x[OFFS5 + n5];
    const int* x6a = (const int*)&x6v;
    int4 x7q[4];
#pragma unroll
    for (int q = 0; q < 4; q++) x7q[q] = x7p[q];
    int4 xls[4][4];
#pragma unroll
    for (int q = 0; q < 4; q++) xls[0][q] = x8v[q];

    // top-down prior to this L5 node (5 steps, runtime child positions)
    float v5 = pit_l[r], pri4 = 0.f;
#pragma unroll
    for (int k = 1; k <= 5; k++) {
      int j = (n5 >> (2 * (5 - k))) & 3;
      v5 = step_down(wtd_l, v5, j, r, h);
      if (k == 4) pri4 = v5;
    }
    float pv5[8];
    oct8(v5, pv5);

    float rat6[4];
#pragma unroll
    for (int q6 = 0; q6 < 4; q6++) {
      if (q6 < 3) {  // prefetch next q6's leaf observations
#pragma unroll
        for (int q = 0; q < 4; q++) xls[q6 + 1][q] = x8v[(q6 + 1) * 4 + q];
      }
      float u6 = dot8(wtd_p[q6], pv5);
      float pv6[8];
      oct8(u6, pv6);
      const int* x7a = (const int*)&x7q[q6];

      float Ep[4][4];
#pragma unroll
      for (int q7 = 0; q7 < 4; q7++) {
        const int* xla = (const int*)&xls[q6][q7];
#pragma unroll
        for (int j = 0; j < 4; j++) Ep[q7][j] = etab_l[(xla[j] * 4 + j) * 32 + r];
      }

      float rat7[4];
#pragma unroll
      for (int q7 = 0; q7 < 4; q7++) {
        float u7 = dot8(wtd_p[q7], pv6);
        float n0 = bfly8(u7 * Ep[q7][0]);
        float n1 = bfly8(u7 * Ep[q7][1]);
        float n2 = bfly8(u7 * Ep[q7][2]);
        float n3 = bfly8(u7 * Ep[q7][3]);
        float p01 = n0 * n1, p23 = n2 * n3;
        float prod = (Ep[q7][0] * Ep[q7][1] * rcpf(p01)) * (Ep[q7][2] * Ep[q7][3] * rcpf(p23));
        acc += __logf(p01) + __logf(p23);
        float em = emt_l[x7a[q7] * 32 + r];
        float nu7 = bfly8(u7 * em * prod);
        acc += __logf(nu7);
        rat7[q7] = em * prod * rcpf(nu7);
      }
      // level-6 node: gather children's rat via DPP, not LDS
      float prod6 = 1.f;
#pragma unroll
      for (int j = 0; j < 4; j++) {
        float pr[8];
        oct8(rat7[j], pr);
        prod6 *= dot8(wup_p[j], pr);
      }
      float em6 = emt_l[x6a[q6] * 32 + r];
      float nu6 = bfly8(u6 * em6 * prod6);
      acc += __logf(nu6);
      rat6[q6] = em6 * prod6 * rcpf(nu6);
    }
    {  // level-5 upward -> rat5buf (cross-group consumers, so LDS)
      float prod5 = 1.f;
#pragma unroll
      for (int j = 0; j < 4; j++) {
        float pr[8];
        oct8(rat6[j], pr);
        prod5 *= dot8(wup_p[j], pr);
      }
      float em5 = emt_l[x5s * 32 + r];
      float nu5 = bfly8(v5 * em5 * prod5);
      acc += __logf(nu5);
      rat5buf[round * 8 + grp][r] = em5 * prod5 * rcpf(nu5);
    }
    if ((grp & 3) == 0) pri4buf[round * 2 + (grp >> 2)][r] = pri4;
  }
  __syncthreads();

  // level-4: 4 nodes per block, groups 0-3
  if (grp < 4) {
    int n4 = b * 4 + grp;
    float prod = 1.f;
#pragma unroll
    for (int j = 0; j < 4; j++) prod *= dot8p(wup_p[j], &rat5buf[grp * 4 + j][g * 8], h);
    float em = emt_l[x[OFFS4 + n4] * 32 + r];
    float pr4 = pri4buf[grp][r];
    float nu = bfly8(pr4 * em * prod);
    acc += __logf(nu);
    AG_ST(&RAT4[n4 * 32 + r], em * prod * rcpf(nu));
  }

  if (s == 0) atomicAdd(&llb[g], acc);
  __syncthreads();
  if (t < 4) AG_ST(&blocksum[b * 4 + t], llb[t]);  // private slot, no RMW
  asm volatile("s_waitcnt vmcnt(0)" ::: "memory");  // stores at coherent point
  __syncthreads();
  if (t == 0) {
    unsigned old = __hip_atomic_fetch_add(&ctr[tree * 32], 1u, __ATOMIC_RELAXED,
                                          __HIP_MEMORY_SCOPE_AGENT);
    // ws is poisoned 0xAA each launch; robust to 0-init too
    lastf = (old == 63u || old == 0xAAAAAAE9u) ? 1 : 0;
  }
  __syncthreads();
  if (!lastf) return;

  // ---------------- phase 2: last block of the tree does levels 3..0 ----------------
  // Stage the tree's RAT4 slice (256 nodes x 32 = 32 KB) into LDS with batched
  // agent loads (pipelined), then all dots hit LDS.
  float* rat4_l = etab_l;
#pragma unroll
  for (int ib = 0; ib < 4; ib++) {
    float tmp[8];
#pragma unroll
    for (int i = 0; i < 8; i++) tmp[i] = AG_LD(&RAT4[tree * 8192 + (ib * 8 + i) * 256 + t]);
#pragma unroll
    for (int i = 0; i < 8; i++) rat4_l[(ib * 8 + i) * 256 + t] = tmp[i];
  }
  if (t < 4) llb[t] = 0.f;
  __syncthreads();

  float* st = &shbuf[grp * 288];
  float acc2 = 0.f;
#pragma unroll 1
  for (int ii = 0; ii < 2; ii++) {
    int l2 = ii * 8 + grp;
    int n2g = tree * 16 + l2;
    float v2 = pit_l[r];
    v2 = step_down(wtd_l, v2, (n2g >> 2) & 3, r, h);
    v2 = step_down(wtd_l, v2, n2g & 3, r, h);
    float pv2[8];
    oct8(v2, pv2);
    float rat3[4];
#pragma unroll
    for (int j3 = 0; j3 < 4; j3++) {
      int n3g = n2g * 4 + j3;       // global level-3 index
      int i3l = l2 * 4 + j3;        // local 0..63
      float p3 = dot8(wtd_p[j3], pv2);
      float prod = 1.f;
#pragma unroll
      for (int j = 0; j < 4; j++) prod *= dot8p(wup_p[j], &rat4_l[(i3l * 4 + j) * 32 + g * 8], h);
      float em = emt_l[x[OFFS3 + n3g] * 32 + r];
      float nu = bfly8(p3 * em * prod);
      acc2 += __logf(nu);
      rat3[j3] = em * prod * rcpf(nu);
    }
    float prod = 1.f;
#pragma unroll
    for (int j = 0; j < 4; j++) {
      float pr[8];
      oct8(rat3[j], pr);
      prod *= dot8(wup_p[j], pr);
    }
    float em = emt_l[x[OFFS2 + n2g] * 32 + r];
    float nu = bfly8(v2 * em * prod);
    acc2 += __logf(nu);
    st[(5 + ii) * 32 + r] = em * prod * rcpf(nu);  // rat2 slot (cross-group)
  }
  __syncthreads();
  if (grp < 4) {  // level 1
    int n1g = tree * 4 + grp;
    float pv[8];
    ld8(pit_l + g * 8, pv);
    float v1 = 0.f;
#pragma unroll
    for (int d = 0; d < 8; d++) v1 += wtd_l[(grp * 8 + d) * 32 + r] * pv[d];
    float prod = 1.f;
#pragma unroll
    for (int j = 0; j < 4; j++) {
      int l2 = grp * 4 + j;
      prod *= dot8p(wup_p[j], &shbuf[(l2 & 7) * 288 + (5 + (l2 >> 3)) * 32 + g * 8], h);
    }
    float em = emt_l[x[OFFS1 + n1g] * 32 + r];
    float nu = bfly8(v1 * em * prod);
    acc2 += __logf(nu);
    st[7 * 32 + r] = em * prod * rcpf(nu);
  }
  __syncthreads();
  if (grp == 0) {  // root
    float pr = pit_l[r];
    float prod = 1.f;
#pragma unroll
    for (int j = 0; j < 4; j++) prod *= dot8p(wup_p[j], &shbuf[j * 288 + 7 * 32 + g * 8], h);
    float em = emt_l[x[tree] * 32 + r];
    float nu = bfly8(pr * em * prod);
    acc2 += __logf(nu);
  }
  __syncthreads();
  if (s == 0) atomicAdd(&llb[g], acc2);
  // reduce this tree's 64 blocks x 4 partial sums (256 values, 1 per thread)
  float v = AG_LD(&blocksum[tree * 256 + t]);
  __syncthreads();
  shbuf[t] = v;
  __syncthreads();
#pragma unroll
  for (int off = 128; off >= 4; off >>= 1) {
    if (t < off) shbuf[t] += shbuf[t + off];
    __syncthreads();
  }
  if (t < 4) out[tree * 4 + t] = shbuf[t] + llb[t];
}

extern "C" void kernel_launch(void* const* d_in, const int* in_sizes, int n_in,
                              void* d_out, int out_size, void* d_ws, size_t ws_size,
                              hipStream_t stream) {
  const int* x = (const int*)d_in[0];
  const float* A = (const float*)d_in[1];
  const float* Bm = (const float*)d_in[2];
  const float* Pi = (const float*)d_in[3];
  float* ws = (float*)d_ws;
  unsigned* ctr = (unsigned*)d_ws;   // 8 trees x stride-32 uints (poison-based count)
  float* blocksum = ws + 256;        // 512 blocks x 4
  float* RAT4 = ws + 256 + 2048;     // 2048*32
  float* out = (float*)d_out;

  k_all<<<512, 256, 0, stream>>>(x, A, Bm, Pi, RAT4, blocksum, ctr, out);
}

// Round 2
// 103.548 us; speedup vs baseline: 1.0222x; 1.0222x over previous
//
#include <hip/hip_runtime.h>

// HTMM: B_TREES=8, ARITY=4, DEPTH=8, C=8, M=100, NGEN=4
constexpr int OFFS1 = 8, OFFS2 = 40, OFFS3 = 168, OFFS4 = 680;
constexpr int OFFS5 = 2728, OFFS6 = 10920, OFFS7 = 43688, OFFS8 = 174760;

// lane mapping within a 32-lane group: r = g*8+s (g = gen, s = state), h = s>>2
// wtd_l[(j*8+d)*32 + g*8+s] = P(child=s | parent=d, pos j, gen g)
// emt_l[m*32 + g*8+c] = P(obs m | state c, gen g);  pit_l[g*8+c] = root prior
// etab_l[(m*4+j)*32 + g*8+d] = sum_c P(c|d,j,g)*em(m|c,g)  (leaf upward operator)
//
// Octet (8-lane) exchanges are pure DPP (quad_perm + row_half_mirror), no LDS,
// no wave barriers -> phase 1 is barrier-free, which lets the TWO independent
// L5 subtrees per group be statement-interleaved (A/B) for 2x ILP: each serial
// chain's DPP/FMA/log latency hides under the sibling subtree's chain.

#define AG_ST(p, v) __hip_atomic_store((p), (v), __ATOMIC_RELAXED, __HIP_MEMORY_SCOPE_AGENT)
#define AG_LD(p) __hip_atomic_load((p), __ATOMIC_RELAXED, __HIP_MEMORY_SCOPE_AGENT)

template <int CTRL>
static __device__ __forceinline__ float dppmov(float v) {
  return __int_as_float(__builtin_amdgcn_update_dpp(0, __float_as_int(v), CTRL, 0xF, 0xF, true));
}

// octet all-reduce sum, result broadcast to all 8 lanes. Pure DPP (no LDS).
static __device__ __forceinline__ float bfly8(float v) {
  v += dppmov<0xB1>(v);   // quad_perm [1,0,3,2]  (xor 1)
  v += dppmov<0x4E>(v);   // quad_perm [2,3,0,1]  (xor 2)
  v += dppmov<0x141>(v);  // row_half_mirror      (cross-quad within octet)
  return v;
}

// gather own-octet values: pv[k] = v[oct | 4h+k], pv[4+k] = v[oct | 7-4h-k]
static __device__ __forceinline__ void oct8(float v, float pv[8]) {
  float m = dppmov<0x141>(v);  // half-mirror: m[l] = v[oct | 7-(l&7)]
  pv[0] = dppmov<0x00>(v); pv[1] = dppmov<0x55>(v);
  pv[2] = dppmov<0xAA>(v); pv[3] = dppmov<0xFF>(v);
  pv[4] = dppmov<0x00>(m); pv[5] = dppmov<0x55>(m);
  pv[6] = dppmov<0xAA>(m); pv[7] = dppmov<0xFF>(m);
}

static __device__ __forceinline__ float dot8(const float w[8], const float v[8]) {
  return w[0]*v[0] + w[1]*v[1] + w[2]*v[2] + w[3]*v[3] +
         w[4]*v[4] + w[5]*v[5] + w[6]*v[6] + w[7]*v[7];
}

static __device__ __forceinline__ void ld8(const float* p, float pv[8]) {
  const float4* q = (const float4*)p;
  float4 a = q[0], b = q[1];
  pv[0] = a.x; pv[1] = a.y; pv[2] = a.z; pv[3] = a.w;
  pv[4] = b.x; pv[5] = b.y; pv[6] = b.z; pv[7] = b.w;
}

// load 8 consecutive floats permuted to the oct8 register order
static __device__ __forceinline__ void ld8p(const float* p, float wp[8], int h) {
  const float4* q = (const float4*)p;
  float4 a = q[h], b = q[1 - h];
  wp[0] = a.x; wp[1] = a.y; wp[2] = a.z; wp[3] = a.w;
  wp[4] = b.w; wp[5] = b.z; wp[6] = b.y; wp[7] = b.x;
}

// dot of permuted weights with a natural-order 8-vector in LDS
static __device__ __forceinline__ float dot8p(const float wp[8], const float* p, int h) {
  const float4* q = (const float4*)p;
  float4 a = q[h], b = q[1 - h];
  return wp[0]*a.x + wp[1]*a.y + wp[2]*a.z + wp[3]*a.w +
         wp[4]*b.w + wp[5]*b.z + wp[6]*b.y + wp[7]*b.x;
}

static __device__ __forceinline__ float dot8r(const float w[8], const float* p) {
  const float4* q = (const float4*)p;
  float4 a = q[0], b = q[1];
  return w[0]*a.x + w[1]*a.y + w[2]*a.z + w[3]*a.w +
         w[4]*b.x + w[5]*b.y + w[6]*b.z + w[7]*b.w;
}

static __device__ __forceinline__ float rcpf(float x) { return __builtin_amdgcn_rcpf(x); }

// one top-down prior step with runtime child-position j (weights read permuted)
static __device__ __forceinline__ float step_down(const float* wtd_l, float v, int j,
                                                  int r, int h) {
  const float* wb = &wtd_l[j * 256 + r];
  float w[8];
#pragma unroll
  for (int k = 0; k < 4; k++) {
    w[k]     = wb[(4 * h + k) * 32];
    w[4 + k] = wb[(7 - 4 * h - k) * 32];
  }
  float pv[8];
  oct8(v, pv);
  return dot8(w, pv);
}

// upward product over 4 children whose rat values live in registers (octet DPP gather)
static __device__ __forceinline__ float upprod(const float wup_p[4][8], const float rat[4]) {
  float prod = 1.f;
#pragma unroll
  for (int j = 0; j < 4; j++) {
    float pr[8];
    oct8(rat[j], pr);
    prod *= dot8(wup_p[j], pr);
  }
  return prod;
}

// level-7 node with its 4 leaf children folded in (Etab operator)
static __device__ __forceinline__ float leaf7(float u7, float e0, float e1, float e2,
                                              float e3, float em, float* acc) {
  float n0 = bfly8(u7 * e0), n1 = bfly8(u7 * e1);
  float n2 = bfly8(u7 * e2), n3 = bfly8(u7 * e3);
  float p01 = n0 * n1, p23 = n2 * n3;
  float prod = (e0 * e1 * rcpf(p01)) * (e2 * e3 * rcpf(p23));
  *acc += __logf(p01) + __logf(p23);
  float nu7 = bfly8(u7 * em * prod);
  *acc += __logf(nu7);
  return em * prod * rcpf(nu7);
}

// Single fused kernel: 512 blocks x 256. Each 32-lane group does 2 level-5
// subtrees CONCURRENTLY (A/B interleaved); block covers 16 L5 nodes = 4 L4
// nodes (done in-block). Last block per tree finishes levels 3..0.
__global__ __launch_bounds__(256) void k_all(const int* __restrict__ x,
                                             const float* __restrict__ A,
                                             const float* __restrict__ Bm,
                                             const float* __restrict__ Pi,
                                             float* __restrict__ RAT4,
                                             float* __restrict__ blocksum,
                                             unsigned* __restrict__ ctr,
                                             float* __restrict__ out) {
  __shared__ __align__(16) float wtd_l[1024];
  __shared__ __align__(16) float emt_l[3200];
  __shared__ __align__(16) float pit_l[32];
  __shared__ __align__(16) float etab_l[12800];  // phase 2 reuses as RAT4 stage
  __shared__ __align__(16) float shbuf[2304];    // phase-2 stash + final reduce
  __shared__ __align__(16) float rat5buf[16][32];
  __shared__ __align__(16) float pri4buf[4][32];
  __shared__ float llb[4];
  __shared__ int lastf;

  int t = threadIdx.x;
  int r = t & 31, g = r >> 3, s = r & 7, grp = t >> 5;
  int h = s >> 2;                       // quad parity within octet
  int b = blockIdx.x, tree = b >> 6;    // 64 blocks per tree

  // ---------------- phase 0: build all tables in LDS (per block) ----------------
  if (t < 128) {  // A softmax over child state; thread owns column (d,j,gg)
    int d = t >> 4, j = (t >> 2) & 3, gg = t & 3;
    float v[8], sum = 0.f;
#pragma unroll
    for (int ss = 0; ss < 8; ss++) { v[ss] = __expf(A[((ss * 8 + d) * 4 + j) * 4 + gg]); sum += v[ss]; }
    float inv = rcpf(sum);
#pragma unroll
    for (int ss = 0; ss < 8; ss++) wtd_l[(j * 8 + d) * 32 + gg * 8 + ss] = v[ss] * inv;
  }
  if (t < 4) {  // Pi softmax
    float v[8], sum = 0.f;
#pragma unroll
    for (int c = 0; c < 8; c++) { v[c] = __expf(Pi[c * 4 + t]); sum += v[c]; }
    float inv = rcpf(sum);
#pragma unroll
    for (int c = 0; c < 8; c++) pit_l[t * 8 + c] = v[c] * inv;
    llb[t] = 0.f;
  }
  {  // emission softmax over m: 32 rows x 8 octet-partitions
    int row = t >> 3, part = t & 7, c = row >> 2, gg = row & 3;
    int m0 = part < 4 ? part * 13 : 52 + (part - 4) * 12;
    int mn = part < 4 ? 13 : 12;
    float sum = 0.f;
    for (int m = m0; m < m0 + mn; m++) sum += __expf(Bm[(c * 100 + m) * 4 + gg]);
    sum = bfly8(sum);
    float inv = rcpf(sum);
    for (int m = m0; m < m0 + mn; m++)
      emt_l[m * 32 + gg * 8 + c] = __expf(Bm[(c * 100 + m) * 4 + gg]) * inv;
  }
  __syncthreads();
  {  // Etab: 12800 entries; combo (j,d,gg) = t&127, m-half = t>>7
    int c7 = t & 127, half = t >> 7;
    int j = c7 >> 5, d = (c7 >> 2) & 7, gg = c7 & 3;
    float w[8];
    ld8(&wtd_l[(j * 8 + d) * 32 + gg * 8], w);
    for (int m = half * 50; m < half * 50 + 50; m++)
      etab_l[(m * 4 + j) * 32 + gg * 8 + d] = dot8r(w, &emt_l[m * 32 + gg * 8]);
  }
  // permuted-order transition registers (wtd_l is stable from here on):
  //  wtd_p[j][i] = P(child=s | parent=perm(i), j, g)  (for parent-sum dots)
  //  wup_p[j][i] = P(child=perm(i) | parent=s, j, g)  (for child-sum dots)
  float wtd_p[4][8], wup_p[4][8];
#pragma unroll
  for (int j = 0; j < 4; j++) {
    const float* wb = &wtd_l[j * 256 + r];
#pragma unroll
    for (int k = 0; k < 4; k++) {
      wtd_p[j][k]     = wb[(4 * h + k) * 32];
      wtd_p[j][4 + k] = wb[(7 - 4 * h - k) * 32];
    }
    ld8p(&wtd_l[(j * 8 + s) * 32 + g * 8], wup_p[j], h);
  }
  __syncthreads();  // etab_l ready

  // ---------------- phase 1: two level-5 subtrees per group, interleaved ----------------
  float acc = 0.f;
  {
    int n5A = b * 16 + grp, n5B = n5A + 8;
    const int4* x8A = (const int4*)(x + OFFS8 + n5A * 64);
    const int4* x8B = (const int4*)(x + OFFS8 + n5B * 64);
    const int4* x7A = (const int4*)(x + OFFS7 + n5A * 16);
    const int4* x7B = (const int4*)(x + OFFS7 + n5B * 16);
    int4 x6A = *(const int4*)(x + OFFS6 + n5A * 4);
    int4 x6B = *(const int4*)(x + OFFS6 + n5B * 4);
    int x5A = x[OFFS5 + n5A], x5B = x[OFFS5 + n5B];
    const int* x6aA = (const int*)&x6A;
    const int* x6aB = (const int*)&x6B;

    // top-down prior to the two L5 nodes (5 steps, runtime child positions)
    float vA = pit_l[r], vB = vA, pri4A = 0.f, pri4B = 0.f;
#pragma unroll
    for (int k = 1; k <= 5; k++) {
      vA = step_down(wtd_l, vA, (n5A >> (2 * (5 - k))) & 3, r, h);
      vB = step_down(wtd_l, vB, (n5B >> (2 * (5 - k))) & 3, r, h);
      if (k == 4) { pri4A = vA; pri4B = vB; }
    }
    float pv5A[8], pv5B[8];
    oct8(vA, pv5A); oct8(vB, pv5B);

    float rat6A[4], rat6B[4];
#pragma unroll
    for (int q6 = 0; q6 < 4; q6++) {
      float u6A = dot8(wtd_p[q6], pv5A);
      float u6B = dot8(wtd_p[q6], pv5B);
      float pv6A[8], pv6B[8];
      oct8(u6A, pv6A); oct8(u6B, pv6B);
      int4 x7qA = x7A[q6], x7qB = x7B[q6];
      const int* x7aA = (const int*)&x7qA;
      const int* x7aB = (const int*)&x7qB;

      float rat7A[4], rat7B[4];
#pragma unroll
      for (int q7 = 0; q7 < 4; q7++) {
        int4 xlA = x8A[q6 * 4 + q7], xlB = x8B[q6 * 4 + q7];
        const int* xa = (const int*)&xlA;
        const int* xb = (const int*)&xlB;
        float EA[4], EB[4];
#pragma unroll
        for (int j = 0; j < 4; j++) {
          EA[j] = etab_l[(xa[j] * 4 + j) * 32 + r];
          EB[j] = etab_l[(xb[j] * 4 + j) * 32 + r];
        }
        float u7A = dot8(wtd_p[q7], pv6A);
        float u7B = dot8(wtd_p[q7], pv6B);
        rat7A[q7] = leaf7(u7A, EA[0], EA[1], EA[2], EA[3], emt_l[x7aA[q7] * 32 + r], &acc);
        rat7B[q7] = leaf7(u7B, EB[0], EB[1], EB[2], EB[3], emt_l[x7aB[q7] * 32 + r], &acc);
      }
      float prod6A = upprod(wup_p, rat7A);
      float prod6B = upprod(wup_p, rat7B);
      float em6A = emt_l[x6aA[q6] * 32 + r];
      float em6B = emt_l[x6aB[q6] * 32 + r];
      float nu6A = bfly8(u6A * em6A * prod6A);
      float nu6B = bfly8(u6B * em6B * prod6B);
      acc += __logf(nu6A) + __logf(nu6B);
      rat6A[q6] = em6A * prod6A * rcpf(nu6A);
      rat6B[q6] = em6B * prod6B * rcpf(nu6B);
    }
    // level-5 upward -> rat5buf (cross-group consumers, so LDS)
    float prod5A = upprod(wup_p, rat6A);
    float prod5B = upprod(wup_p, rat6B);
    float em5A = emt_l[x5A * 32 + r], em5B = emt_l[x5B * 32 + r];
    float nu5A = bfly8(vA * em5A * prod5A);
    float nu5B = bfly8(vB * em5B * prod5B);
    acc += __logf(nu5A) + __logf(nu5B);
    rat5buf[grp][r] = em5A * prod5A * rcpf(nu5A);
    rat5buf[8 + grp][r] = em5B * prod5B * rcpf(nu5B);
    if ((grp & 3) == 0) {
      pri4buf[grp >> 2][r] = pri4A;
      pri4buf[2 + (grp >> 2)][r] = pri4B;
    }
  }
  __syncthreads();

  // level-4: 4 nodes per block, groups 0-3
  if (grp < 4) {
    int n4 = b * 4 + grp;
    float prod = 1.f;
#pragma unroll
    for (int j = 0; j < 4; j++) prod *= dot8p(wup_p[j], &rat5buf[grp * 4 + j][g * 8], h);
    float em = emt_l[x[OFFS4 + n4] * 32 + r];
    float pr4 = pri4buf[grp][r];
    float nu = bfly8(pr4 * em * prod);
    acc += __logf(nu);
    AG_ST(&RAT4[n4 * 32 + r], em * prod * rcpf(nu));
  }

  if (s == 0) atomicAdd(&llb[g], acc);
  __syncthreads();
  if (t < 4) AG_ST(&blocksum[b * 4 + t], llb[t]);  // private slot, no RMW
  asm volatile("s_waitcnt vmcnt(0)" ::: "memory");  // stores at coherent point
  __syncthreads();
  if (t == 0) {
    unsigned old = __hip_atomic_fetch_add(&ctr[tree * 32], 1u, __ATOMIC_RELAXED,
                                          __HIP_MEMORY_SCOPE_AGENT);
    // ws is poisoned 0xAA each launch; robust to 0-init too
    lastf = (old == 63u || old == 0xAAAAAAE9u) ? 1 : 0;
  }
  __syncthreads();
  if (!lastf) return;

  // ---------------- phase 2: last block of the tree does levels 3..0 ----------------
  // Stage the tree's RAT4 slice (256 nodes x 32 = 32 KB) into LDS with batched
  // agent loads (pipelined), then all dots hit LDS.
  float* rat4_l = etab_l;
#pragma unroll
  for (int ib = 0; ib < 4; ib++) {
    float tmp[8];
#pragma unroll
    for (int i = 0; i < 8; i++) tmp[i] = AG_LD(&RAT4[tree * 8192 + (ib * 8 + i) * 256 + t]);
#pragma unroll
    for (int i = 0; i < 8; i++) rat4_l[(ib * 8 + i) * 256 + t] = tmp[i];
  }
  if (t < 4) llb[t] = 0.f;
  __syncthreads();

  float* st = &shbuf[grp * 288];
  float acc2 = 0.f;
  {  // two level-2 subtrees per group, interleaved (A: l2=grp, B: l2=8+grp)
    int n2A = tree * 16 + grp, n2B = n2A + 8;
    int4 x3A = *(const int4*)(x + OFFS3 + n2A * 4);
    int4 x3B = *(const int4*)(x + OFFS3 + n2B * 4);
    int x2A = x[OFFS2 + n2A], x2B = x[OFFS2 + n2B];
    const int* xa = (const int*)&x3A;
    const int* xb = (const int*)&x3B;
    float v2A = pit_l[r], v2B = v2A;
    v2A = step_down(wtd_l, v2A, (n2A >> 2) & 3, r, h);
    v2B = step_down(wtd_l, v2B, (n2B >> 2) & 3, r, h);
    v2A = step_down(wtd_l, v2A, n2A & 3, r, h);
    v2B = step_down(wtd_l, v2B, n2B & 3, r, h);
    float pv2A[8], pv2B[8];
    oct8(v2A, pv2A); oct8(v2B, pv2B);
    float rat3A[4], rat3B[4];
#pragma unroll
    for (int j3 = 0; j3 < 4; j3++) {
      int i3A = grp * 4 + j3, i3B = (8 + grp) * 4 + j3;
      float p3A = dot8(wtd_p[j3], pv2A);
      float p3B = dot8(wtd_p[j3], pv2B);
      float prodA = 1.f, prodB = 1.f;
#pragma unroll
      for (int j = 0; j < 4; j++) {
        prodA *= dot8p(wup_p[j], &rat4_l[(i3A * 4 + j) * 32 + g * 8], h);
        prodB *= dot8p(wup_p[j], &rat4_l[(i3B * 4 + j) * 32 + g * 8], h);
      }
      float emA = emt_l[xa[j3] * 32 + r], emB = emt_l[xb[j3] * 32 + r];
      float nuA = bfly8(p3A * emA * prodA), nuB = bfly8(p3B * emB * prodB);
      acc2 += __logf(nuA) + __logf(nuB);
      rat3A[j3] = emA * prodA * rcpf(nuA);
      rat3B[j3] = emB * prodB * rcpf(nuB);
    }
    float prodA = upprod(wup_p, rat3A);
    float prodB = upprod(wup_p, rat3B);
    float emA = emt_l[x2A * 32 + r], emB = emt_l[x2B * 32 + r];
    float nuA = bfly8(v2A * emA * prodA), nuB = bfly8(v2B * emB * prodB);
    acc2 += __logf(nuA) + __logf(nuB);
    st[5 * 32 + r] = emA * prodA * rcpf(nuA);  // rat2 slots (cross-group)
    st[6 * 32 + r] = emB * prodB * rcpf(nuB);
  }
  __syncthreads();
  if (grp < 4) {  // level 1
    int n1g = tree * 4 + grp;
    float pv[8];
    ld8(pit_l + g * 8, pv);
    float v1 = 0.f;
#pragma unroll
    for (int d = 0; d < 8; d++) v1 += wtd_l[(grp * 8 + d) * 32 + r] * pv[d];
    float prod = 1.f;
#pragma unroll
    for (int j = 0; j < 4; j++) {
      int l2 = grp * 4 + j;
      prod *= dot8p(wup_p[j], &shbuf[(l2 & 7) * 288 + (5 + (l2 >> 3)) * 32 + g * 8], h);
    }
    float em = emt_l[x[OFFS1 + n1g] * 32 + r];
    float nu = bfly8(v1 * em * prod);
    acc2 += __logf(nu);
    st[7 * 32 + r] = em * prod * rcpf(nu);
  }
  __syncthreads();
  if (grp == 0) {  // root
    float pr = pit_l[r];
    float prod = 1.f;
#pragma unroll
    for (int j = 0; j < 4; j++) prod *= dot8p(wup_p[j], &shbuf[j * 288 + 7 * 32 + g * 8], h);
    float em = emt_l[x[tree] * 32 + r];
    float nu = bfly8(pr * em * prod);
    acc2 += __logf(nu);
  }
  __syncthreads();
  if (s == 0) atomicAdd(&llb[g], acc2);
  // reduce this tree's 64 blocks x 4 partial sums (256 values, 1 per thread)
  float v = AG_LD(&blocksum[tree * 256 + t]);
  __syncthreads();
  shbuf[t] = v;
  __syncthreads();
#pragma unroll
  for (int off = 128; off >= 4; off >>= 1) {
    if (t < off) shbuf[t] += shbuf[t + off];
    __syncthreads();
  }
  if (t < 4) out[tree * 4 + t] = shbuf[t] + llb[t];
}

extern "C" void kernel_launch(void* const* d_in, const int* in_sizes, int n_in,
                              void* d_out, int out_size, void* d_ws, size_t ws_size,
                              hipStream_t stream) {
  const int* x = (const int*)d_in[0];
  const float* A = (const float*)d_in[1];
  const float* Bm = (const float*)d_in[2];
  const float* Pi = (const float*)d_in[3];
  float* ws = (float*)d_ws;
  unsigned* ctr = (unsigned*)d_ws;   // 8 trees x stride-32 uints (poison-based count)
  float* blocksum = ws + 256;        // 512 blocks x 4
  float* RAT4 = ws + 256 + 2048;     // 2048*32
  float* out = (float*)d_out;

  k_all<<<512, 256, 0, stream>>>(x, A, Bm, Pi, RAT4, blocksum, ctr, out);
}

// Round 3
// 91.488 us; speedup vs baseline: 1.1570x; 1.1318x over previous
//
#include <hip/hip_runtime.h>

// HTMM: B_TREES=8, ARITY=4, DEPTH=8, C=8, M=100, NGEN=4
constexpr int OFFS1 = 8, OFFS2 = 40, OFFS3 = 168, OFFS4 = 680;
constexpr int OFFS5 = 2728, OFFS6 = 10920, OFFS7 = 43688, OFFS8 = 174760;

// lane mapping within a 32-lane group: r = g*8+s (g = gen, s = state), h = s>>2
// wtd_l[(j*8+d)*32 + g*8+s] = P(child=s | parent=d, pos j, gen g)
// emt_l[m*32 + g*8+c] = P(obs m | state c, gen g);  pit_l[g*8+c] = root prior
//
// Octet (8-lane) exchanges are pure DPP (quad_perm + row_half_mirror), no LDS,
// no wave barriers; two independent L5 subtrees per group are statement-
// interleaved (A/B) for 2x ILP. The leaf operator (old 51 KB etab table) is
// computed on the fly: dot8p(wup_p[j], emt row) with register weights — this
// cuts LDS from 80 KB to ~45 KB so 2-3 blocks/CU are co-resident (single
// dispatch batch instead of two sequential batches of 256 blocks).

#define AG_ST(p, v) __hip_atomic_store((p), (v), __ATOMIC_RELAXED, __HIP_MEMORY_SCOPE_AGENT)
#define AG_LD(p) __hip_atomic_load((p), __ATOMIC_RELAXED, __HIP_MEMORY_SCOPE_AGENT)

template <int CTRL>
static __device__ __forceinline__ float dppmov(float v) {
  return __int_as_float(__builtin_amdgcn_update_dpp(0, __float_as_int(v), CTRL, 0xF, 0xF, true));
}

// octet all-reduce sum, result broadcast to all 8 lanes. Pure DPP (no LDS).
static __device__ __forceinline__ float bfly8(float v) {
  v += dppmov<0xB1>(v);   // quad_perm [1,0,3,2]  (xor 1)
  v += dppmov<0x4E>(v);   // quad_perm [2,3,0,1]  (xor 2)
  v += dppmov<0x141>(v);  // row_half_mirror      (cross-quad within octet)
  return v;
}

// gather own-octet values: pv[k] = v[oct | 4h+k], pv[4+k] = v[oct | 7-4h-k]
static __device__ __forceinline__ void oct8(float v, float pv[8]) {
  float m = dppmov<0x141>(v);  // half-mirror: m[l] = v[oct | 7-(l&7)]
  pv[0] = dppmov<0x00>(v); pv[1] = dppmov<0x55>(v);
  pv[2] = dppmov<0xAA>(v); pv[3] = dppmov<0xFF>(v);
  pv[4] = dppmov<0x00>(m); pv[5] = dppmov<0x55>(m);
  pv[6] = dppmov<0xAA>(m); pv[7] = dppmov<0xFF>(m);
}

static __device__ __forceinline__ float dot8(const float w[8], const float v[8]) {
  return w[0]*v[0] + w[1]*v[1] + w[2]*v[2] + w[3]*v[3] +
         w[4]*v[4] + w[5]*v[5] + w[6]*v[6] + w[7]*v[7];
}

static __device__ __forceinline__ void ld8(const float* p, float pv[8]) {
  const float4* q = (const float4*)p;
  float4 a = q[0], b = q[1];
  pv[0] = a.x; pv[1] = a.y; pv[2] = a.z; pv[3] = a.w;
  pv[4] = b.x; pv[5] = b.y; pv[6] = b.z; pv[7] = b.w;
}

// load 8 consecutive floats permuted to the oct8 register order
static __device__ __forceinline__ void ld8p(const float* p, float wp[8], int h) {
  const float4* q = (const float4*)p;
  float4 a = q[h], b = q[1 - h];
  wp[0] = a.x; wp[1] = a.y; wp[2] = a.z; wp[3] = a.w;
  wp[4] = b.w; wp[5] = b.z; wp[6] = b.y; wp[7] = b.x;
}

// dot of permuted weights with a natural-order 8-vector in LDS
static __device__ __forceinline__ float dot8p(const float wp[8], const float* p, int h) {
  const float4* q = (const float4*)p;
  float4 a = q[h], b = q[1 - h];
  return wp[0]*a.x + wp[1]*a.y + wp[2]*a.z + wp[3]*a.w +
         wp[4]*b.w + wp[5]*b.z + wp[6]*b.y + wp[7]*b.x;
}

static __device__ __forceinline__ float rcpf(float x) { return __builtin_amdgcn_rcpf(x); }

// one top-down prior step with runtime child-position j (weights read permuted)
static __device__ __forceinline__ float step_down(const float* wtd_l, float v, int j,
                                                  int r, int h) {
  const float* wb = &wtd_l[j * 256 + r];
  float w[8];
#pragma unroll
  for (int k = 0; k < 4; k++) {
    w[k]     = wb[(4 * h + k) * 32];
    w[4 + k] = wb[(7 - 4 * h - k) * 32];
  }
  float pv[8];
  oct8(v, pv);
  return dot8(w, pv);
}

// upward product over 4 children whose rat values live in registers (octet DPP gather)
static __device__ __forceinline__ float upprod(const float wup_p[4][8], const float rat[4]) {
  float prod = 1.f;
#pragma unroll
  for (int j = 0; j < 4; j++) {
    float pr[8];
    oct8(rat[j], pr);
    prod *= dot8(wup_p[j], pr);
  }
  return prod;
}

// level-7 node with its 4 leaf children folded in
static __device__ __forceinline__ float leaf7(float u7, float e0, float e1, float e2,
                                              float e3, float em, float* acc) {
  float n0 = bfly8(u7 * e0), n1 = bfly8(u7 * e1);
  float n2 = bfly8(u7 * e2), n3 = bfly8(u7 * e3);
  float p01 = n0 * n1, p23 = n2 * n3;
  float prod = (e0 * e1 * rcpf(p01)) * (e2 * e3 * rcpf(p23));
  *acc += __logf(p01) + __logf(p23);
  float nu7 = bfly8(u7 * em * prod);
  *acc += __logf(nu7);
  return em * prod * rcpf(nu7);
}

// Single fused kernel: 512 blocks x 256. Each 32-lane group does 2 level-5
// subtrees CONCURRENTLY (A/B interleaved); block covers 16 L5 nodes = 4 L4
// nodes (done in-block). Last block per tree finishes levels 3..0.
__global__ __launch_bounds__(256) void k_all(const int* __restrict__ x,
                                             const float* __restrict__ A,
                                             const float* __restrict__ Bm,
                                             const float* __restrict__ Pi,
                                             float* __restrict__ RAT4,
                                             float* __restrict__ blocksum,
                                             unsigned* __restrict__ ctr,
                                             float* __restrict__ out) {
  __shared__ __align__(16) float wtd_l[1024];
  __shared__ __align__(16) float emt_l[3200];
  __shared__ __align__(16) float pit_l[32];
  __shared__ __align__(16) float stg[4096];   // phase-2 RAT4 half-stage (16 KB)
  __shared__ __align__(16) float shbuf[2304]; // phase-2 stash + final reduce
  __shared__ __align__(16) float rat5buf[16][32];
  __shared__ __align__(16) float pri4buf[4][32];
  __shared__ float llb[4];
  __shared__ int lastf;

  int t = threadIdx.x;
  int r = t & 31, g = r >> 3, s = r & 7, grp = t >> 5;
  int h = s >> 2;                       // quad parity within octet
  int gb = g * 8;                       // octet base within a 32-row
  int b = blockIdx.x, tree = b >> 6;    // 64 blocks per tree

  // ---------------- phase 0: build tables in LDS (per block) ----------------
  if (t < 128) {  // A softmax over child state; thread owns column (d,j,gg)
    int d = t >> 4, j = (t >> 2) & 3, gg = t & 3;
    float v[8], sum = 0.f;
#pragma unroll
    for (int ss = 0; ss < 8; ss++) { v[ss] = __expf(A[((ss * 8 + d) * 4 + j) * 4 + gg]); sum += v[ss]; }
    float inv = rcpf(sum);
#pragma unroll
    for (int ss = 0; ss < 8; ss++) wtd_l[(j * 8 + d) * 32 + gg * 8 + ss] = v[ss] * inv;
  }
  if (t < 4) {  // Pi softmax
    float v[8], sum = 0.f;
#pragma unroll
    for (int c = 0; c < 8; c++) { v[c] = __expf(Pi[c * 4 + t]); sum += v[c]; }
    float inv = rcpf(sum);
#pragma unroll
    for (int c = 0; c < 8; c++) pit_l[t * 8 + c] = v[c] * inv;
    llb[t] = 0.f;
  }
  {  // emission softmax over m: 32 rows x 8 octet-partitions
    int row = t >> 3, part = t & 7, c = row >> 2, gg = row & 3;
    int m0 = part < 4 ? part * 13 : 52 + (part - 4) * 12;
    int mn = part < 4 ? 13 : 12;
    float sum = 0.f;
    for (int m = m0; m < m0 + mn; m++) sum += __expf(Bm[(c * 100 + m) * 4 + gg]);
    sum = bfly8(sum);
    float inv = rcpf(sum);
    for (int m = m0; m < m0 + mn; m++)
      emt_l[m * 32 + gg * 8 + c] = __expf(Bm[(c * 100 + m) * 4 + gg]) * inv;
  }
  __syncthreads();
  // permuted-order transition registers (wtd_l stable from here on):
  //  wtd_p[j][i] = P(child=s | parent=perm(i), j, g)  (for parent-sum dots)
  //  wup_p[j][i] = P(child=perm(i) | parent=s, j, g)  (for child-sum dots)
  float wtd_p[4][8], wup_p[4][8];
#pragma unroll
  for (int j = 0; j < 4; j++) {
    const float* wb = &wtd_l[j * 256 + r];
#pragma unroll
    for (int k = 0; k < 4; k++) {
      wtd_p[j][k]     = wb[(4 * h + k) * 32];
      wtd_p[j][4 + k] = wb[(7 - 4 * h - k) * 32];
    }
    ld8p(&wtd_l[(j * 8 + s) * 32 + gb], wup_p[j], h);
  }

  // ---------------- phase 1: two level-5 subtrees per group, interleaved ----------------
  float acc = 0.f;
  {
    int n5A = b * 16 + grp, n5B = n5A + 8;
    const int4* x8A = (const int4*)(x + OFFS8 + n5A * 64);
    const int4* x8B = (const int4*)(x + OFFS8 + n5B * 64);
    const int4* x7A = (const int4*)(x + OFFS7 + n5A * 16);
    const int4* x7B = (const int4*)(x + OFFS7 + n5B * 16);
    int4 x6A = *(const int4*)(x + OFFS6 + n5A * 4);
    int4 x6B = *(const int4*)(x + OFFS6 + n5B * 4);
    int x5A = x[OFFS5 + n5A], x5B = x[OFFS5 + n5B];
    const int* x6aA = (const int*)&x6A;
    const int* x6aB = (const int*)&x6B;

    // top-down prior to the two L5 nodes (5 steps, runtime child positions)
    float vA = pit_l[r], vB = vA, pri4A = 0.f, pri4B = 0.f;
#pragma unroll
    for (int k = 1; k <= 5; k++) {
      vA = step_down(wtd_l, vA, (n5A >> (2 * (5 - k))) & 3, r, h);
      vB = step_down(wtd_l, vB, (n5B >> (2 * (5 - k))) & 3, r, h);
      if (k == 4) { pri4A = vA; pri4B = vB; }
    }
    float pv5A[8], pv5B[8];
    oct8(vA, pv5A); oct8(vB, pv5B);

    float rat6A[4], rat6B[4];
#pragma unroll
    for (int q6 = 0; q6 < 4; q6++) {
      float u6A = dot8(wtd_p[q6], pv5A);
      float u6B = dot8(wtd_p[q6], pv5B);
      float pv6A[8], pv6B[8];
      oct8(u6A, pv6A); oct8(u6B, pv6B);
      int4 x7qA = x7A[q6], x7qB = x7B[q6];
      const int* x7aA = (const int*)&x7qA;
      const int* x7aB = (const int*)&x7qB;

      float rat7A[4], rat7B[4];
#pragma unroll
      for (int q7 = 0; q7 < 4; q7++) {
        int4 xlA = x8A[q6 * 4 + q7], xlB = x8B[q6 * 4 + q7];
        const int* xa = (const int*)&xlA;
        const int* xb = (const int*)&xlB;
        // leaf operator on the fly: E = sum_c P(c|s,j,g) em(m|c,g)
        float EA[4], EB[4];
#pragma unroll
        for (int j = 0; j < 4; j++) {
          EA[j] = dot8p(wup_p[j], &emt_l[xa[j] * 32 + gb], h);
          EB[j] = dot8p(wup_p[j], &emt_l[xb[j] * 32 + gb], h);
        }
        float u7A = dot8(wtd_p[q7], pv6A);
        float u7B = dot8(wtd_p[q7], pv6B);
        rat7A[q7] = leaf7(u7A, EA[0], EA[1], EA[2], EA[3], emt_l[x7aA[q7] * 32 + r], &acc);
        rat7B[q7] = leaf7(u7B, EB[0], EB[1], EB[2], EB[3], emt_l[x7aB[q7] * 32 + r], &acc);
      }
      float prod6A = upprod(wup_p, rat7A);
      float prod6B = upprod(wup_p, rat7B);
      float em6A = emt_l[x6aA[q6] * 32 + r];
      float em6B = emt_l[x6aB[q6] * 32 + r];
      float nu6A = bfly8(u6A * em6A * prod6A);
      float nu6B = bfly8(u6B * em6B * prod6B);
      acc += __logf(nu6A) + __logf(nu6B);
      rat6A[q6] = em6A * prod6A * rcpf(nu6A);
      rat6B[q6] = em6B * prod6B * rcpf(nu6B);
    }
    // level-5 upward -> rat5buf (cross-group consumers, so LDS)
    float prod5A = upprod(wup_p, rat6A);
    float prod5B = upprod(wup_p, rat6B);
    float em5A = emt_l[x5A * 32 + r], em5B = emt_l[x5B * 32 + r];
    float nu5A = bfly8(vA * em5A * prod5A);
    float nu5B = bfly8(vB * em5B * prod5B);
    acc += __logf(nu5A) + __logf(nu5B);
    rat5buf[grp][r] = em5A * prod5A * rcpf(nu5A);
    rat5buf[8 + grp][r] = em5B * prod5B * rcpf(nu5B);
    if ((grp & 3) == 0) {
      pri4buf[grp >> 2][r] = pri4A;
      pri4buf[2 + (grp >> 2)][r] = pri4B;
    }
  }
  __syncthreads();

  // level-4: 4 nodes per block, groups 0-3
  if (grp < 4) {
    int n4 = b * 4 + grp;
    float prod = 1.f;
#pragma unroll
    for (int j = 0; j < 4; j++) prod *= dot8p(wup_p[j], &rat5buf[grp * 4 + j][gb], h);
    float em = emt_l[x[OFFS4 + n4] * 32 + r];
    float pr4 = pri4buf[grp][r];
    float nu = bfly8(pr4 * em * prod);
    acc += __logf(nu);
    AG_ST(&RAT4[n4 * 32 + r], em * prod * rcpf(nu));
  }

  if (s == 0) atomicAdd(&llb[g], acc);
  __syncthreads();
  if (t < 4) AG_ST(&blocksum[b * 4 + t], llb[t]);  // private slot, no RMW
  asm volatile("s_waitcnt vmcnt(0)" ::: "memory");  // stores at coherent point
  __syncthreads();
  if (t == 0) {
    unsigned old = __hip_atomic_fetch_add(&ctr[tree * 32], 1u, __ATOMIC_RELAXED,
                                          __HIP_MEMORY_SCOPE_AGENT);
    // ws is poisoned 0xAA each launch; robust to 0-init too
    lastf = (old == 63u || old == 0xAAAAAAE9u) ? 1 : 0;
  }
  __syncthreads();
  if (!lastf) return;

  // ---------------- phase 2: last block of the tree does levels 3..0 ----------------
  // RAT4 slice staged in two 16 KB halves; second half prefetched to registers
  // before computing the first so its latency hides under compute.
  float tmpA[16], tmpB[16];
#pragma unroll
  for (int i = 0; i < 16; i++) tmpA[i] = AG_LD(&RAT4[tree * 8192 + i * 256 + t]);
#pragma unroll
  for (int i = 0; i < 16; i++) stg[i * 256 + t] = tmpA[i];
#pragma unroll
  for (int i = 0; i < 16; i++) tmpB[i] = AG_LD(&RAT4[tree * 8192 + 4096 + i * 256 + t]);
  if (t < 4) llb[t] = 0.f;
  __syncthreads();  // first half staged

  float* st = &shbuf[grp * 288];
  float acc2 = 0.f;
  // ----- A half: l2 = grp (rows 0..127 of the tree's RAT4 slice) -----
  {
    int n2A = tree * 16 + grp;
    int4 x3A = *(const int4*)(x + OFFS3 + n2A * 4);
    int x2A = x[OFFS2 + n2A];
    const int* xa = (const int*)&x3A;
    float v2A = pit_l[r];
    v2A = step_down(wtd_l, v2A, (n2A >> 2) & 3, r, h);
    v2A = step_down(wtd_l, v2A, n2A & 3, r, h);
    float pv2A[8];
    oct8(v2A, pv2A);
    float rat3A[4];
#pragma unroll
    for (int j3 = 0; j3 < 4; j3++) {
      float p3A = dot8(wtd_p[j3], pv2A);
      float prodA = 1.f;
#pragma unroll
      for (int j = 0; j < 4; j++)
        prodA *= dot8p(wup_p[j], &stg[(grp * 16 + j3 * 4 + j) * 32 + gb], h);
      float emA = emt_l[xa[j3] * 32 + r];
      float nuA = bfly8(p3A * emA * prodA);
      acc2 += __logf(nuA);
      rat3A[j3] = emA * prodA * rcpf(nuA);
    }
    float prodA = upprod(wup_p, rat3A);
    float emA = emt_l[x2A * 32 + r];
    float nuA = bfly8(v2A * emA * prodA);
    acc2 += __logf(nuA);
    st[5 * 32 + r] = emA * prodA * rcpf(nuA);  // rat2 slot A (cross-group)
  }
  __syncthreads();  // everyone done reading half A
#pragma unroll
  for (int i = 0; i < 16; i++) stg[i * 256 + t] = tmpB[i];
  __syncthreads();  // second half staged
  // ----- B half: l2 = 8+grp (rows 128..255; same local row formula) -----
  {
    int n2B = tree * 16 + 8 + grp;
    int4 x3B = *(const int4*)(x + OFFS3 + n2B * 4);
    int x2B = x[OFFS2 + n2B];
    const int* xb = (const int*)&x3B;
    float v2B = pit_l[r];
    v2B = step_down(wtd_l, v2B, (n2B >> 2) & 3, r, h);
    v2B = step_down(wtd_l, v2B, n2B & 3, r, h);
    float pv2B[8];
    oct8(v2B, pv2B);
    float rat3B[4];
#pragma unroll
    for (int j3 = 0; j3 < 4; j3++) {
      float p3B = dot8(wtd_p[j3], pv2B);
      float prodB = 1.f;
#pragma unroll
      for (int j = 0; j < 4; j++)
        prodB *= dot8p(wup_p[j], &stg[(grp * 16 + j3 * 4 + j) * 32 + gb], h);
      float emB = emt_l[xb[j3] * 32 + r];
      float nuB = bfly8(p3B * emB * prodB);
      acc2 += __logf(nuB);
      rat3B[j3] = emB * prodB * rcpf(nuB);
    }
    float prodB = upprod(wup_p, rat3B);
    float emB = emt_l[x2B * 32 + r];
    float nuB = bfly8(v2B * emB * prodB);
    acc2 += __logf(nuB);
    st[6 * 32 + r] = emB * prodB * rcpf(nuB);  // rat2 slot B (cross-group)
  }
  __syncthreads();
  if (grp < 4) {  // level 1
    int n1g = tree * 4 + grp;
    float pv[8];
    ld8(pit_l + gb, pv);
    float v1 = 0.f;
#pragma unroll
    for (int d = 0; d < 8; d++) v1 += wtd_l[(grp * 8 + d) * 32 + r] * pv[d];
    float prod = 1.f;
#pragma unroll
    for (int j = 0; j < 4; j++) {
      int l2 = grp * 4 + j;
      prod *= dot8p(wup_p[j], &shbuf[(l2 & 7) * 288 + (5 + (l2 >> 3)) * 32 + gb], h);
    }
    float em = emt_l[x[OFFS1 + n1g] * 32 + r];
    float nu = bfly8(v1 * em * prod);
    acc2 += __logf(nu);
    st[7 * 32 + r] = em * prod * rcpf(nu);
  }
  __syncthreads();
  if (grp == 0) {  // root
    float pr = pit_l[r];
    float prod = 1.f;
#pragma unroll
    for (int j = 0; j < 4; j++) prod *= dot8p(wup_p[j], &shbuf[j * 288 + 7 * 32 + gb], h);
    float em = emt_l[x[tree] * 32 + r];
    float nu = bfly8(pr * em * prod);
    acc2 += __logf(nu);
  }
  __syncthreads();
  if (s == 0) atomicAdd(&llb[g], acc2);
  // reduce this tree's 64 blocks x 4 partial sums (256 values, 1 per thread)
  float v = AG_LD(&blocksum[tree * 256 + t]);
  __syncthreads();
  shbuf[t] = v;
  __syncthreads();
#pragma unroll
  for (int off = 128; off >= 4; off >>= 1) {
    if (t < off) shbuf[t] += shbuf[t + off];
    __syncthreads();
  }
  if (t < 4) out[tree * 4 + t] = shbuf[t] + llb[t];
}

extern "C" void kernel_launch(void* const* d_in, const int* in_sizes, int n_in,
                              void* d_out, int out_size, void* d_ws, size_t ws_size,
                              hipStream_t stream) {
  const int* x = (const int*)d_in[0];
  const float* A = (const float*)d_in[1];
  const float* Bm = (const float*)d_in[2];
  const float* Pi = (const float*)d_in[3];
  float* ws = (float*)d_ws;
  unsigned* ctr = (unsigned*)d_ws;   // 8 trees x stride-32 uints (poison-based count)
  float* blocksum = ws + 256;        // 512 blocks x 4
  float* RAT4 = ws + 256 + 2048;     // 2048*32
  float* out = (float*)d_out;

  k_all<<<512, 256, 0, stream>>>(x, A, Bm, Pi, RAT4, blocksum, ctr, out);
}